// Round 2
// baseline (266.896 us; speedup 1.0000x reference)
//
#include <hip/hip_runtime.h>

typedef __attribute__((ext_vector_type(8))) short s16x8;            // 8 bf16 (MFMA A/B frag)
typedef __attribute__((ext_vector_type(8))) unsigned short u16x8;   // 16 B vector
typedef __attribute__((ext_vector_type(4))) float f32x4;            // MFMA C/D frag

#define ALPHA_F 0.36787944117144233f
#define BETA_F  0.36787944117144233f
#define OMB_F   0.63212055882855767f   /* 1 - beta */

#define XS_PSTR  40     /* pos stride in u16: 80 B breaks the 128-B bank fold (was 32 -> 8-way conflict) */
#define XS_RSTR  720    /* row stride = 18 * XS_PSTR */
#define XS_U16   7200   /* one staging buffer: 180 pos x XS_PSTR u16 = 14400 B (2 bufs = 28800 B <= ys 33280 B) */
#define YS_STRIDE 130   /* epilogue row pad: bank stride 65 dwords (odd) */

__device__ __forceinline__ unsigned short f2bf(float f){
  union { float f; unsigned int u; } v; v.f = f;
  unsigned int u = v.u;
  return (unsigned short)((u + 0x7FFFu + ((u >> 16) & 1u)) >> 16);  // RNE
}
__device__ __forceinline__ float bf2f(unsigned short s){
  union { unsigned int u; float f; } v; v.u = ((unsigned int)s) << 16;
  return v.f;
}

// ---- Kernel 0: W (co,ci,3,3) fp32 -> Wr bf16 [pos9][cic4][co128][cil32] ----
__global__ __launch_bounds__(256) void reorder_w(const float* __restrict__ W,
                                                 unsigned short* __restrict__ Wr){
  int f = blockIdx.x * 256 + threadIdx.x;
  if (f >= 9*128*128) return;
  int cil = f & 31;
  int co  = (f >> 5) & 127;
  int cic = (f >> 12) & 3;
  int pos = f >> 14;
  int ci  = (cic << 5) | cil;
  Wr[f] = f2bf(W[(co*128 + ci)*9 + pos]);
}

// ---- Kernel 1: fully fused conv3x3 (bf16 MFMA, NCHW fp32 input) + IIR ----
// grid (7,14,16). Block = 128 co x 128 pixels (8x16 patch), 4 waves.
// Wave w computes co [32w,32w+32) x all 128 pixels: acc[2 mt][8 nt].
// Staging: in-kernel gather/transpose NCHW fp32 -> xs[pos][ci32] bf16, dbuf.
// xs pos-stride padded to 40 u16 (80 B): 64 B stride folded mod 128 B into
// 2 phases per 16-lane group -> 8-way bank conflict on every B ds_read_b128
// and WBUF ds_write_b128. 80 B gives 8 distinct phases -> residual 2-way (free).
__global__ __launch_bounds__(256, 3) void conv_lif(
    const float* __restrict__ x,
    const unsigned short* __restrict__ Wr,
    const float* __restrict__ bias,
    float* __restrict__ out)
{
  // xs double buffer 2 x 14400 B; epilogue ys[128][130] aliases (33280 B)
  __shared__ unsigned short sm[128*YS_STRIDE];
  const int tid  = threadIdx.x;
  const int lane = tid & 63;
  const int wid  = tid >> 6;         // wave id = co block (32 co each)
  const int l15  = lane & 15;
  const int quad = lane >> 4;
  const int bz = blockIdx.z;
  const int h0 = blockIdx.y * 8, w0 = blockIdx.x * 16;

  const float* xb = x + (size_t)bz * 1605632;   // x[bz][ci][h][w]

  // ---- gather geometry: 720 units (pos 180 x cq 4), <=3 per thread ----
  int  g_off[3], g_ci0[3];
  bool g_val[3];
  #pragma unroll
  for (int it = 0; it < 3; ++it){
    int u = tid + it*256;
    bool act = (u < 720);
    int uu = act ? u : 0;
    int pos = uu >> 2, cq = uu & 3;
    int row = pos / 18, col = pos - row*18;
    int gh = h0 - 1 + row, gw = w0 - 1 + col;
    bool val = act && (gh >= 0) && (gh < 112) && (gw >= 0) && (gw < 112);
    g_off[it] = val ? (gh*112 + gw) : 0;
    g_ci0[it] = cq << 3;
    g_val[it] = val;
  }

  u16x8 g[3];
  #define GATHER(cic_) do{ \
    _Pragma("unroll") \
    for (int it = 0; it < 3; ++it){ \
      const float* p = xb + (size_t)(g_ci0[it] + ((cic_) << 5)) * 12544 + g_off[it]; \
      u16x8 v; \
      _Pragma("unroll") \
      for (int k = 0; k < 8; ++k){ \
        float f = p[(size_t)k * 12544]; \
        f = g_val[it] ? f : 0.0f; \
        v[k] = f2bf(f); \
      } \
      g[it] = v; \
    } }while(0)

  #define WBUF(buf_) do{ \
    unsigned short* xw = sm + (buf_)*XS_U16; \
    _Pragma("unroll") \
    for (int it = 0; it < 3; ++it){ \
      int u = tid + it*256; \
      if (u < 720) *(u16x8*)(xw + (u >> 2)*XS_PSTR + ((u & 3) << 3)) = g[it]; \
    } }while(0)

  f32x4 acc[2][8];
  #pragma unroll
  for (int i = 0; i < 2; ++i)
    #pragma unroll
    for (int j = 0; j < 8; ++j) acc[i][j] = (f32x4){0.f,0.f,0.f,0.f};

  GATHER(0); WBUF(0);

  for (int cic = 0; cic < 4; ++cic){
    __syncthreads();                        // xs[cic&1] visible; prev readers done
    const unsigned short* xs = sm + (cic & 1)*XS_U16;
    #pragma unroll
    for (int dw = 0; dw < 3; ++dw){
      // A-frags (L2-resident Wr): af[dh][mt], co = wid*32 + mt*16 + l15
      s16x8 af[3][2];
      #pragma unroll
      for (int dh = 0; dh < 3; ++dh){
        const unsigned short* wp = Wr + ((((dh*3 + dw) << 2) + cic) << 12)
                                      + (((wid << 5) + l15) << 5) + (quad << 3);
        af[dh][0] = *(const s16x8*)wp;
        af[dh][1] = *(const s16x8*)(wp + 512);
      }
      // B rows: ring of 6, rows r = nt+dh in [0,10); col = l15+dw, ci = quad*8+
      const unsigned short* bcol = xs + (l15 + dw)*XS_PSTR + (quad << 3);
      s16x8 R[6];
      #pragma unroll
      for (int r = 0; r < 4; ++r) R[r] = *(const s16x8*)(bcol + r*XS_RSTR);
      #pragma unroll
      for (int p = 0; p < 4; ++p){
        if (p < 3){
          R[(2*p+4) % 6] = *(const s16x8*)(bcol + (2*p+4)*XS_RSTR);
          R[(2*p+5) % 6] = *(const s16x8*)(bcol + (2*p+5)*XS_RSTR);
        }
        #pragma unroll
        for (int dh = 0; dh < 3; ++dh){
          #pragma unroll
          for (int sub = 0; sub < 2; ++sub){
            int nt = 2*p + sub;
            s16x8 b = R[(nt + dh) % 6];
            acc[0][nt] = __builtin_amdgcn_mfma_f32_16x16x32_bf16(af[dh][0], b, acc[0][nt], 0, 0, 0);
            acc[1][nt] = __builtin_amdgcn_mfma_f32_16x16x32_bf16(af[dh][1], b, acc[1][nt], 0, 0, 0);
          }
        }
      }
      // issue next chunk's gathers after dw=1: dw=2's A-loads are already in
      // flight (vmcnt order), and dw=2's ~930 MFMA cycles hide gather latency.
      if (dw == 1 && cic < 3) GATHER(cic+1);
    }
    if (cic < 3) WBUF((cic+1) & 1);         // pack waits on gathers here
  }

  __syncthreads();                          // done with xs; alias as ys
  // C/D layout: col(n=pix)=lane&15, row(m)=quad*4+reg; co = wid*32+mt*16+m
  #pragma unroll
  for (int mt = 0; mt < 2; ++mt){
    int cobase = (wid << 5) + (mt << 4) + (quad << 2);
    float4 bv = *(const float4*)(bias + cobase);
    #pragma unroll
    for (int nt = 0; nt < 8; ++nt){
      int pix = (nt << 4) + l15;
      f32x4 a = acc[mt][nt];
      ushort2 w01, w23;
      w01.x = f2bf(a.x + bv.x);
      w01.y = f2bf(a.y + bv.y);
      w23.x = f2bf(a.z + bv.z);
      w23.y = f2bf(a.w + bv.w);
      unsigned short* yp = sm + pix*YS_STRIDE + cobase;
      *(ushort2*)(yp)     = w01;
      *(ushort2*)(yp + 2) = w23;
    }
  }
  __syncthreads();

  // temporal IIR along t=co per pixel: s=alpha*s+y; m=beta*m+(1-beta)*s
  // half 1 warm-starts at t=48 (alpha^16 ~ 1e-7 << bf16 noise).
  {
    int pix  = tid & 127;
    int half = tid >> 7;
    int r = pix >> 4, c = pix & 15;
    float s = 0.f, m = 0.f;
    float* op = out + (size_t)bz*1605632 + (h0 + r)*112 + (w0 + c);
    const unsigned short* yr = sm + pix*YS_STRIDE;
    int t0     = half ? 48 : 0;
    int tstore = half ? 64 : 0;
    int tend   = half ? 128 : 64;
    for (int t = t0; t < tend; ++t){
      float y = bf2f(yr[t]);
      s = ALPHA_F * s + y;
      m = BETA_F  * m + OMB_F * s;
      if (t >= tstore) op[(size_t)t*12544] = m;   // 64 B runs along w
    }
  }
  #undef GATHER
  #undef WBUF
}

extern "C" void kernel_launch(void* const* d_in, const int* in_sizes, int n_in,
                              void* d_out, int out_size, void* d_ws, size_t ws_size,
                              hipStream_t stream){
  const float* x = (const float*)d_in[0];
  const float* W = (const float*)d_in[1];
  const float* b = (const float*)d_in[2];
  float* out = (float*)d_out;
  unsigned short* Wr = (unsigned short*)d_ws;    // 294912 B
  reorder_w<<<576, 256, 0, stream>>>(W, Wr);
  conv_lif<<<dim3(7, 14, 16), 256, 0, stream>>>(x, Wr, b, out);
}